// Round 23
// baseline (234.110 us; speedup 1.0000x reference)
//
#include <hip/hip_runtime.h>

using f16 = _Float16;
typedef _Float16 h8 __attribute__((ext_vector_type(8)));
typedef _Float16 h4 __attribute__((ext_vector_type(4)));
typedef float f32x4 __attribute__((ext_vector_type(4)));
typedef float f32x16 __attribute__((ext_vector_type(16)));
typedef unsigned u32x4 __attribute__((ext_vector_type(4)));

constexpr int L_SEQ  = 2048;
constexpr int NBATCH = 4;
constexpr int EMB    = 1024;
constexpr int NHEAD  = 16;
constexpr int HDIM   = 64;
constexpr int BH     = NBATCH * NHEAD;   // 64 head-batches
constexpr int MROWS  = L_SEQ * NBATCH;   // 8192

// Q pre-scale: 1/sqrt(HD) * log2(e)  (softmax done in exp2 domain)
#define QSCALE (0.125f * 1.44269504088896341f)

__device__ __forceinline__ void glds16(const void* g, void* l) {
  __builtin_amdgcn_global_load_lds(
      (const __attribute__((address_space(1))) void*)g,
      (__attribute__((address_space(3))) void*)l, 16, 0, 0);
}

__device__ __forceinline__ f32x16 MFMA32(h8 a, h8 b, f32x16 c) {
  return __builtin_amdgcn_mfma_f32_32x32x16_f16(a, b, c, 0, 0, 0);
}
__device__ __forceinline__ unsigned pkrtz(float x, float y) {
  auto t = __builtin_amdgcn_cvt_pkrtz(x, y);   // __fp16 ext_vector(2)
  return __builtin_bit_cast(unsigned, t);
}
__device__ __forceinline__ h8 pack8(f32x4 a, f32x4 b) {
  u32x4 u = { pkrtz(a[0], a[1]), pkrtz(a[2], a[3]),
              pkrtz(b[0], b[1]), pkrtz(b[2], b[3]) };
  return __builtin_bit_cast(h8, u);
}

// ---------------- f32 -> f16 convert (weights only) ----------------
__global__ __launch_bounds__(256)
void convert_w_kernel(const float* __restrict__ w, const float* __restrict__ wo,
                      f16* __restrict__ wb, f16* __restrict__ wob) {
  const int NW  = 3 * EMB * EMB / 4;
  const int NWO = EMB * EMB / 4;
  const int total = NW + NWO;
  int i = blockIdx.x * blockDim.x + threadIdx.x;
  const int stride = gridDim.x * blockDim.x;
  for (; i < total; i += stride) {
    const float* s; f16* d; int j;
    if (i < NW) { s = w;  d = wb;  j = i;      }
    else        { s = wo; d = wob; j = i - NW; }
    float4 t = reinterpret_cast<const float4*>(s)[j];
    h4 o = { (f16)t.x, (f16)t.y, (f16)t.z, (f16)t.w };
    reinterpret_cast<h4*>(d)[j] = o;
  }
}

// ---------------- in-proj GEMM: f32 A reg-staged + packed to f16 LDS ----------------
__global__ __launch_bounds__(256)
void gemm_qkv(const float* __restrict__ qin, const float* __restrict__ kin,
              const float* __restrict__ vin, const f16* __restrict__ Btbase,
              const float* __restrict__ biasbase, f16* __restrict__ Hbase)
{
  const int id = blockIdx.x;
  const int x   = id & 7;            // XCD
  const int bnI = (id >> 3) & 7;     // column tile, varies fastest per XCD
  const int bmG = x + 8 * (id >> 6); // global row panel 0..191
  const int z   = bmG >> 6;          // 0..2 (q/k/v)
  const int bm  = (bmG & 63) * 128;
  const int bn  = bnI * 128;

  const float* A = (z == 0) ? qin : (z == 1) ? kin : vin;
  const f16* Bt = Btbase + (size_t)z * EMB * EMB;
  const float* bias = biasbase + (size_t)z * EMB;

  const int t = threadIdx.x;
  const int w = t >> 6, lane = t & 63;
  const int wr = w >> 1, wc = w & 1;
  const int l16 = lane & 15, g = lane >> 4;

  __shared__ f16 As[2][128][32];
  __shared__ f16 Bs[2][128][32];

  f32x4 acc[4][4] = {};

  const int sr0 = lane >> 2;
  const int sl  = lane & 3;
  const float* gA = &A[(size_t)(bm + w*32 + sr0) * EMB + sl*8];
  const int wslot = 8 * (sl ^ ((sr0 >> 1) & 3));
  f16* lA0 = &As[0][w*32 + sr0][wslot];
  f16* lA0b = &As[0][w*32 + 16 + sr0][wslot];
  const int asStride = 128 * 32;

  const int sr  = lane >> 2;
  const int sc8 = 8 * ((lane & 3) ^ ((lane >> 3) & 3));
  const f16* gB = &Bt[(size_t)(bn + w*32 + sr) * EMB + sc8];

  f32x4 ra0, ra1, rb0, rb1;
  f32x4 sa0, sa1, sb0, sb1;

  ra0 = *(const f32x4*)(gA);
  ra1 = *(const f32x4*)(gA + 4);
  rb0 = *(const f32x4*)(gA + (size_t)16*EMB);
  rb1 = *(const f32x4*)(gA + (size_t)16*EMB + 4);
  *(h8*)lA0  = pack8(ra0, ra1);
  *(h8*)lA0b = pack8(rb0, rb1);
  glds16(gB, &Bs[0][w*32][0]);
  glds16(gB + (size_t)16*EMB, &Bs[0][w*32 + 16][0]);
  sa0 = *(const f32x4*)(gA + 32);
  sa1 = *(const f32x4*)(gA + 36);
  sb0 = *(const f32x4*)(gA + (size_t)16*EMB + 32);
  sb1 = *(const f32x4*)(gA + (size_t)16*EMB + 36);
  glds16(gB + 32, &Bs[1][w*32][0]);
  glds16(gB + (size_t)16*EMB + 32, &Bs[1][w*32 + 16][0]);
  __syncthreads();

  const int fswz = (g ^ ((l16 >> 1) & 3)) * 8;

#pragma unroll 2
  for (int i = 0; i < 32; ++i) {
    const int cur = i & 1;
    if (i < 30) {
      const int k0 = (i + 2) * 32;
      ra0 = *(const f32x4*)(gA + k0);
      ra1 = *(const f32x4*)(gA + k0 + 4);
      rb0 = *(const f32x4*)(gA + (size_t)16*EMB + k0);
      rb1 = *(const f32x4*)(gA + (size_t)16*EMB + k0 + 4);
    }
    if (i < 31) {
      const int k0 = (i + 1) * 32;
      glds16(gB + k0, &Bs[cur ^ 1][w*32][0]);
      glds16(gB + (size_t)16*EMB + k0, &Bs[cur ^ 1][w*32 + 16][0]);
    }

    h8 af[4], bfr[4];
#pragma unroll
    for (int m = 0; m < 4; ++m) af[m]  = *(const h8*)&As[cur][wr*64 + m*16 + l16][fswz];
#pragma unroll
    for (int n = 0; n < 4; ++n) bfr[n] = *(const h8*)&Bs[cur][wc*64 + n*16 + l16][fswz];
    __builtin_amdgcn_s_setprio(1);
#pragma unroll
    for (int m = 0; m < 4; ++m)
#pragma unroll
      for (int n = 0; n < 4; ++n)
        acc[m][n] = __builtin_amdgcn_mfma_f32_16x16x32_f16(af[m], bfr[n], acc[m][n], 0, 0, 0);
    __builtin_amdgcn_s_setprio(0);

    if (i < 31) {
      f16* d0 = lA0  + (cur ^ 1) * asStride;
      f16* d1 = lA0b + (cur ^ 1) * asStride;
      *(h8*)d0 = pack8(sa0, sa1);
      *(h8*)d1 = pack8(sb0, sb1);
      sa0 = ra0; sa1 = ra1; sb0 = rb0; sb1 = rb1;
    }
    __syncthreads();
  }

#pragma unroll
  for (int m = 0; m < 4; ++m) {
#pragma unroll
    for (int n = 0; n < 4; ++n) {
      const int col = bn + wc*64 + n*16 + l16;
      const float bv = bias[col];
#pragma unroll
      for (int r = 0; r < 4; ++r) {
        const int row = bm + wr*64 + m*16 + g*4 + r;
        float v = acc[m][n][r] + bv;
        if (z == 0) v *= QSCALE;
        const int l = row >> 2, nn = row & 3;
        const int h = col >> 6, hd = col & 63;
        Hbase[(((size_t)z * BH + nn * NHEAD + h) * L_SEQ + l) * HDIM + hd] = (f16)v;
      }
    }
  }
}

// ---------------- out-proj GEMM (f16 A), dbuf, A+B bank-swizzled ----------------
__global__ __launch_bounds__(256)
void gemm_out(const f16* __restrict__ A, const f16* __restrict__ Bt,
              const float* __restrict__ bias, float* __restrict__ Fout)
{
  const int id = blockIdx.x;
  const int x   = id & 7;
  const int bnI = (id >> 3) & 7;
  const int bmG = x + 8 * (id >> 6);   // 0..63
  const int bm  = bmG * 128;
  const int bn  = bnI * 128;

  const int t = threadIdx.x;
  const int w = t >> 6, lane = t & 63;
  const int wr = w >> 1, wc = w & 1;
  const int l16 = lane & 15, g = lane >> 4;

  __shared__ f16 As[2][128][32];
  __shared__ f16 Bs[2][128][32];

  f32x4 acc[4][4] = {};

  const int sr  = lane >> 2;
  const int sc8 = 8 * ((lane & 3) ^ ((lane >> 3) & 3));
  const f16* gA = &A [(size_t)(bm + w*32 + sr) * EMB + sc8];
  const f16* gB = &Bt[(size_t)(bn + w*32 + sr) * EMB + sc8];

  glds16(gA, &As[0][w*32][0]);
  glds16(gA + (size_t)16*EMB, &As[0][w*32 + 16][0]);
  glds16(gB, &Bs[0][w*32][0]);
  glds16(gB + (size_t)16*EMB, &Bs[0][w*32 + 16][0]);
  __syncthreads();

  const int fswz = (g ^ ((l16 >> 1) & 3)) * 8;

#pragma unroll 1
  for (int i = 0; i < 32; ++i) {
    const int cur = i & 1;
    if (i < 31) {
      const int k0 = (i + 1) * 32;
      glds16(gA + k0, &As[cur ^ 1][w*32][0]);
      glds16(gA + (size_t)16*EMB + k0, &As[cur ^ 1][w*32 + 16][0]);
      glds16(gB + k0, &Bs[cur ^ 1][w*32][0]);
      glds16(gB + (size_t)16*EMB + k0, &Bs[cur ^ 1][w*32 + 16][0]);
    }

    h8 af[4], bfr[4];
#pragma unroll
    for (int m = 0; m < 4; ++m) af[m]  = *(const h8*)&As[cur][wr*64 + m*16 + l16][fswz];
#pragma unroll
    for (int n = 0; n < 4; ++n) bfr[n] = *(const h8*)&Bs[cur][wc*64 + n*16 + l16][fswz];
    __builtin_amdgcn_s_setprio(1);
#pragma unroll
    for (int m = 0; m < 4; ++m)
#pragma unroll
      for (int n = 0; n < 4; ++n)
        acc[m][n] = __builtin_amdgcn_mfma_f32_16x16x32_f16(af[m], bfr[n], acc[m][n], 0, 0, 0);
    __builtin_amdgcn_s_setprio(0);
    __syncthreads();
  }

#pragma unroll
  for (int m = 0; m < 4; ++m) {
#pragma unroll
    for (int n = 0; n < 4; ++n) {
      const int col = bn + wc*64 + n*16 + l16;
      const float bv = bias[col];
#pragma unroll
      for (int r = 0; r < 4; ++r) {
        const int row = bm + wr*64 + m*16 + g*4 + r;
        Fout[(size_t)row * EMB + col] = acc[m][n][r] + bv;
      }
    }
  }
}

// ---------------- V transpose: [BH][L][HD] -> [BH][HD][L] ----------------
__global__ __launch_bounds__(256)
void vtrans_kernel(const f16* __restrict__ V, f16* __restrict__ Vt) {
  const int b = blockIdx.y;
  const int t = threadIdx.x;
  const int d = t & 63;
  const int l0 = (blockIdx.x * 4 + (t >> 6)) * 8;
  const f16* Vb = V  + (size_t)b * L_SEQ * HDIM;
  f16* Vtb      = Vt + (size_t)b * L_SEQ * HDIM;
  h8 v;
#pragma unroll
  for (int i = 0; i < 8; ++i) v[i] = Vb[(size_t)(l0 + i) * HDIM + d];
  *(h8*)&Vtb[(size_t)d * L_SEQ + l0] = v;
}

// ---------------- Flash attention v13: 2 q-tiles/wave, KVBLK=128 ----------------
// 128-row K/V chunks: barriers halve (16 total), 64 MFMA + deep independent
// QK/PV streams per chunk. K tile [128][64] row&7-swizzle; V tile [64][128]
// row&15-swizzle (2-way, free). LDS 64 KB -> 2 blocks/CU (unchanged).
__device__ __forceinline__ void expack(const f32x16& acc, float (&ps)[4],
                                       h8& paA, h8& paB) {
#pragma unroll
  for (int half = 0; half < 2; ++half) {
    float p0 = __builtin_amdgcn_exp2f(acc[half*8+0]);
    float p1 = __builtin_amdgcn_exp2f(acc[half*8+1]);
    float p2 = __builtin_amdgcn_exp2f(acc[half*8+2]);
    float p3 = __builtin_amdgcn_exp2f(acc[half*8+3]);
    float p4 = __builtin_amdgcn_exp2f(acc[half*8+4]);
    float p5 = __builtin_amdgcn_exp2f(acc[half*8+5]);
    float p6 = __builtin_amdgcn_exp2f(acc[half*8+6]);
    float p7 = __builtin_amdgcn_exp2f(acc[half*8+7]);
    ps[0] += p0 + p4;
    ps[1] += p1 + p5;
    ps[2] += p2 + p6;
    ps[3] += p3 + p7;
    unsigned A = pkrtz(p0, p1);
    unsigned C = pkrtz(p2, p3);
    unsigned B = pkrtz(p4, p5);
    unsigned D = pkrtz(p6, p7);
    asm("v_permlane32_swap_b32 %0, %1" : "+v"(A), "+v"(B));
    asm("v_permlane32_swap_b32 %0, %1" : "+v"(C), "+v"(D));
    u32x4 wv = { A, C, B, D };
    h8 r = __builtin_bit_cast(h8, wv);
    if (half == 0) paA = r; else paB = r;
  }
}

__device__ __forceinline__ void attn13_step(
    const f16* __restrict__ Kc, const f16* __restrict__ Vc,
    const h8 (&qf0)[4], const h8 (&qf1)[4],
    f32x16 (&o0)[2], f32x16 (&o1)[2],
    float (&ps0)[4], float (&ps1)[4],
    int l31, int hi)
{
  const int kswz = (l31 & 7) << 3;    // K tile [128][64]: slot ^ (row&7)
  const int vswz = (l31 & 15) << 3;   // V tile [64][128]: slot ^ (row&15)

  // per kt (4 x 32 k-rows): QK for both q-tiles, then exp2+pack
  h8 pa0[8], pa1[8];
#pragma unroll
  for (int kt = 0; kt < 4; ++kt) {
    h8 kf[4];
#pragma unroll
    for (int s = 0; s < 4; ++s)
      kf[s] = *(const h8*)&Kc[(kt*32 + l31)*64 + ((s*16 + hi*8) ^ kswz)];

    f32x16 acc0 = {};
    f32x16 acc1 = {};
    __builtin_amdgcn_s_setprio(1);
#pragma unroll
    for (int s = 0; s < 4; ++s) {
      acc0 = MFMA32(kf[s], qf0[s], acc0);
      acc1 = MFMA32(kf[s], qf1[s], acc1);
    }
    __builtin_amdgcn_s_setprio(0);

    expack(acc0, ps0, pa0[kt*2], pa0[kt*2+1]);
    expack(acc1, ps1, pa1[kt*2], pa1[kt*2+1]);
  }

  // PV over 8 k-slices of 16
#pragma unroll
  for (int s2 = 0; s2 < 8; ++s2) {
    h8 vf0 = *(const h8*)&Vc[(0*32 + l31)*128 + ((s2*16 + hi*8) ^ vswz)];
    h8 vf1 = *(const h8*)&Vc[(1*32 + l31)*128 + ((s2*16 + hi*8) ^ vswz)];
    __builtin_amdgcn_s_setprio(1);
    o0[0] = MFMA32(pa0[s2], vf0, o0[0]);
    o0[1] = MFMA32(pa0[s2], vf1, o0[1]);
    o1[0] = MFMA32(pa1[s2], vf0, o1[0]);
    o1[1] = MFMA32(pa1[s2], vf1, o1[1]);
    __builtin_amdgcn_s_setprio(0);
  }
}

__global__ __launch_bounds__(256, 2)
void attn13_kernel(const f16* __restrict__ Qh, const f16* __restrict__ Kh,
                   const f16* __restrict__ Vt, f16* __restrict__ AO)
{
  // 512 blocks: 8 XCD x 8 qblk x 8 head-groups; 8 heads per XCD (L2 locality)
  const int id = blockIdx.x;
  const int b    = (id & 7) | ((id >> 6) << 3);
  const int qblk = (id >> 3) & 7;

  const int t = threadIdx.x;
  const int w = t >> 6, lane = t & 63;
  const int l31 = lane & 31, hi = lane >> 5;

  const f16* Qb = Qh + (size_t)b * L_SEQ * HDIM;
  const f16* Kb = Kh + (size_t)b * L_SEQ * HDIM;
  const f16* Vb = Vt + (size_t)b * (size_t)HDIM * L_SEQ;

  __shared__ f16 Ks[2][128*64];   // 32 KB (row&7-swizzled slots)
  __shared__ f16 Vs[2][64*128];   // 32 KB (row&15-swizzled slots)

  const int q0 = qblk * 256 + w * 32;   // this wave's q-tiles: q0 and q0+128

  h8 qf0[4], qf1[4];
#pragma unroll
  for (int s = 0; s < 4; ++s) {
    qf0[s] = *(const h8*)&Qb[(size_t)(q0 + l31) * HDIM + s*16 + hi*8];
    qf1[s] = *(const h8*)&Qb[(size_t)(q0 + 128 + l31) * HDIM + s*16 + hi*8];
  }

  // K staging: wave w covers rows [w*32, w*32+32) in 4 8-row issues
  const int srow = lane >> 3;                 // 0..7
  const int scol = 8 * ((lane & 7) ^ srow);   // pre-swizzled source col
  const f16* gK = Kb + (size_t)(w*32 + srow) * HDIM + scol;

  // V staging: wave w covers d-rows [w*16, w*16+16) in 4 4-row issues
  const int vrl = lane >> 4;                  // 0..3 (row within issue)
  const f16* gV[4];
#pragma unroll
  for (int i = 0; i < 4; ++i) {
    const int drow = w*16 + i*4 + vrl;
    gV[i] = Vb + (size_t)drow * L_SEQ + 8 * ((lane & 15) ^ (drow & 15));
  }

  f32x16 o0[2] = {};
  f32x16 o1[2] = {};
  float ps0[4] = { 0.f, 0.f, 0.f, 0.f };
  float ps1[4] = { 0.f, 0.f, 0.f, 0.f };

  // prologue: stage chunk 0 into buf 0
#pragma unroll
  for (int i = 0; i < 4; ++i) {
    glds16(gK + (size_t)i*8*HDIM, &Ks[0][(w*32 + i*8)*64]);
    glds16(gV[i], &Vs[0][(w*16 + i*4)*128]);
  }
  __syncthreads();

#pragma unroll 1
  for (int j0 = 0; j0 < L_SEQ; j0 += 256) {
    {
      const int jn = (j0 + 128) & (L_SEQ - 1);
#pragma unroll
      for (int i = 0; i < 4; ++i) {
        glds16(gK + (size_t)(jn + i*8)*HDIM, &Ks[1][(w*32 + i*8)*64]);
        glds16(gV[i] + jn, &Vs[1][(w*16 + i*4)*128]);
      }
      attn13_step(&Ks[0][0], &Vs[0][0], qf0, qf1, o0, o1, ps0, ps1, l31, hi);
      __syncthreads();
    }
    {
      const int jn = (j0 + 256) & (L_SEQ - 1);
#pragma unroll
      for (int i = 0; i < 4; ++i) {
        glds16(gK + (size_t)(jn + i*8)*HDIM, &Ks[0][(w*32 + i*8)*64]);
        glds16(gV[i] + jn, &Vs[0][(w*16 + i*4)*128]);
      }
      attn13_step(&Ks[1][0], &Vs[1][0], qf0, qf1, o0, o1, ps0, ps1, l31, hi);
      __syncthreads();
    }
  }

  // ---- epilogue (two q-tiles) ----
  const int nn = b >> 4, h = b & 15;
  float ssum0 = (ps0[0] + ps0[1]) + (ps0[2] + ps0[3]);
  ssum0 += __shfl_xor(ssum0, 32);
  const float inv0 = 1.0f / ssum0;
  float ssum1 = (ps1[0] + ps1[1]) + (ps1[2] + ps1[3]);
  ssum1 += __shfl_xor(ssum1, 32);
  const float inv1 = 1.0f / ssum1;

#pragma unroll
  for (int r = 0; r < 16; ++r) {
    const int qrow = (r & 3) + 8 * (r >> 2) + 4 * hi;
    {
      const float iv = __shfl(inv0, qrow);
      const int lr = q0 + qrow;
#pragma unroll
      for (int dt = 0; dt < 2; ++dt)
        AO[((size_t)lr * NBATCH + nn) * EMB + h*HDIM + dt*32 + l31] =
            (f16)(o0[dt][r] * iv);
    }
    {
      const float iv = __shfl(inv1, qrow);
      const int lr = q0 + 128 + qrow;
#pragma unroll
      for (int dt = 0; dt < 2; ++dt)
        AO[((size_t)lr * NBATCH + nn) * EMB + h*HDIM + dt*32 + l31] =
            (f16)(o1[dt][r] * iv);
    }
  }
}

// ---------------- launch ----------------
extern "C" void kernel_launch(void* const* d_in, const int* in_sizes, int n_in,
                              void* d_out, int out_size, void* d_ws, size_t ws_size,
                              hipStream_t stream) {
  const float* query = (const float*)d_in[0];
  const float* key   = (const float*)d_in[1];
  const float* value = (const float*)d_in[2];
  const float* in_w  = (const float*)d_in[3];
  const float* in_b  = (const float*)d_in[4];
  const float* out_w = (const float*)d_in[5];
  const float* out_b = (const float*)d_in[6];
  float* out = (float*)d_out;

  char* ws = (char*)d_ws;
  size_t offH  = 0;
  size_t offX  = offH  + (size_t)3 * BH * L_SEQ * HDIM * 2;
  size_t offW  = offX  + (size_t)3 * MROWS * EMB * 2;
  size_t offWo = offW  + (size_t)3 * EMB * EMB * 2;
  size_t offAO = offWo + (size_t)EMB * EMB * 2;
  f16* Hbase = (f16*)(ws + offH);
  f16* Xb    = (f16*)(ws + offX);   // region reused for Vt only
  f16* Wb    = (f16*)(ws + offW);
  f16* Wob   = (f16*)(ws + offWo);
  f16* AOb   = (f16*)(ws + offAO);
  f16* Vtb   = Xb;

  hipLaunchKernelGGL(convert_w_kernel, dim3(1024), dim3(256), 0, stream,
                     in_w, out_w, Wb, Wob);

  hipLaunchKernelGGL(gemm_qkv, dim3(1536), dim3(256), 0, stream,
                     query, key, value, Wb, in_b, Hbase);

  f16* Vh = Hbase + (size_t)2 * BH * L_SEQ * HDIM;
  hipLaunchKernelGGL(vtrans_kernel, dim3(L_SEQ/32, BH), dim3(256), 0, stream, Vh, Vtb);

  hipLaunchKernelGGL(attn13_kernel, dim3(512), dim3(256), 0, stream,
                     Hbase,
                     Hbase + (size_t)BH * L_SEQ * HDIM,
                     Vtb, AOb);

  hipLaunchKernelGGL(gemm_out, dim3(512), dim3(256), 0, stream,
                     AOb, Wob, out_b, out);
}

// Round 24
// 207.342 us; speedup vs baseline: 1.1291x; 1.1291x over previous
//
#include <hip/hip_runtime.h>

using f16 = _Float16;
typedef _Float16 h8 __attribute__((ext_vector_type(8)));
typedef _Float16 h4 __attribute__((ext_vector_type(4)));
typedef float f32x4 __attribute__((ext_vector_type(4)));
typedef float f32x16 __attribute__((ext_vector_type(16)));
typedef unsigned u32x4 __attribute__((ext_vector_type(4)));

constexpr int L_SEQ  = 2048;
constexpr int NBATCH = 4;
constexpr int EMB    = 1024;
constexpr int NHEAD  = 16;
constexpr int HDIM   = 64;
constexpr int BH     = NBATCH * NHEAD;   // 64 head-batches
constexpr int MROWS  = L_SEQ * NBATCH;   // 8192

// Q pre-scale: 1/sqrt(HD) * log2(e)  (softmax done in exp2 domain)
#define QSCALE (0.125f * 1.44269504088896341f)

__device__ __forceinline__ void glds16(const void* g, void* l) {
  __builtin_amdgcn_global_load_lds(
      (const __attribute__((address_space(1))) void*)g,
      (__attribute__((address_space(3))) void*)l, 16, 0, 0);
}

__device__ __forceinline__ f32x16 MFMA32(h8 a, h8 b, f32x16 c) {
  return __builtin_amdgcn_mfma_f32_32x32x16_f16(a, b, c, 0, 0, 0);
}
__device__ __forceinline__ unsigned pkrtz(float x, float y) {
  auto t = __builtin_amdgcn_cvt_pkrtz(x, y);   // __fp16 ext_vector(2)
  return __builtin_bit_cast(unsigned, t);
}
__device__ __forceinline__ h8 pack8(f32x4 a, f32x4 b) {
  u32x4 u = { pkrtz(a[0], a[1]), pkrtz(a[2], a[3]),
              pkrtz(b[0], b[1]), pkrtz(b[2], b[3]) };
  return __builtin_bit_cast(h8, u);
}

// ---------------- f32 -> f16 convert (weights only) ----------------
__global__ __launch_bounds__(256)
void convert_w_kernel(const float* __restrict__ w, const float* __restrict__ wo,
                      f16* __restrict__ wb, f16* __restrict__ wob) {
  const int NW  = 3 * EMB * EMB / 4;
  const int NWO = EMB * EMB / 4;
  const int total = NW + NWO;
  int i = blockIdx.x * blockDim.x + threadIdx.x;
  const int stride = gridDim.x * blockDim.x;
  for (; i < total; i += stride) {
    const float* s; f16* d; int j;
    if (i < NW) { s = w;  d = wb;  j = i;      }
    else        { s = wo; d = wob; j = i - NW; }
    float4 t = reinterpret_cast<const float4*>(s)[j];
    h4 o = { (f16)t.x, (f16)t.y, (f16)t.z, (f16)t.w };
    reinterpret_cast<h4*>(d)[j] = o;
  }
}

// ---------------- in-proj GEMM: f32 A reg-staged + packed to f16 LDS ----------------
__global__ __launch_bounds__(256)
void gemm_qkv(const float* __restrict__ qin, const float* __restrict__ kin,
              const float* __restrict__ vin, const f16* __restrict__ Btbase,
              const float* __restrict__ biasbase, f16* __restrict__ Hbase)
{
  const int id = blockIdx.x;
  const int x   = id & 7;            // XCD
  const int bnI = (id >> 3) & 7;     // column tile, varies fastest per XCD
  const int bmG = x + 8 * (id >> 6); // global row panel 0..191
  const int z   = bmG >> 6;          // 0..2 (q/k/v)
  const int bm  = (bmG & 63) * 128;
  const int bn  = bnI * 128;

  const float* A = (z == 0) ? qin : (z == 1) ? kin : vin;
  const f16* Bt = Btbase + (size_t)z * EMB * EMB;
  const float* bias = biasbase + (size_t)z * EMB;

  const int t = threadIdx.x;
  const int w = t >> 6, lane = t & 63;
  const int wr = w >> 1, wc = w & 1;
  const int l16 = lane & 15, g = lane >> 4;

  __shared__ f16 As[2][128][32];
  __shared__ f16 Bs[2][128][32];

  f32x4 acc[4][4] = {};

  const int sr0 = lane >> 2;
  const int sl  = lane & 3;
  const float* gA = &A[(size_t)(bm + w*32 + sr0) * EMB + sl*8];
  const int wslot = 8 * (sl ^ ((sr0 >> 1) & 3));
  f16* lA0 = &As[0][w*32 + sr0][wslot];
  f16* lA0b = &As[0][w*32 + 16 + sr0][wslot];
  const int asStride = 128 * 32;

  const int sr  = lane >> 2;
  const int sc8 = 8 * ((lane & 3) ^ ((lane >> 3) & 3));
  const f16* gB = &Bt[(size_t)(bn + w*32 + sr) * EMB + sc8];

  f32x4 ra0, ra1, rb0, rb1;
  f32x4 sa0, sa1, sb0, sb1;

  ra0 = *(const f32x4*)(gA);
  ra1 = *(const f32x4*)(gA + 4);
  rb0 = *(const f32x4*)(gA + (size_t)16*EMB);
  rb1 = *(const f32x4*)(gA + (size_t)16*EMB + 4);
  *(h8*)lA0  = pack8(ra0, ra1);
  *(h8*)lA0b = pack8(rb0, rb1);
  glds16(gB, &Bs[0][w*32][0]);
  glds16(gB + (size_t)16*EMB, &Bs[0][w*32 + 16][0]);
  sa0 = *(const f32x4*)(gA + 32);
  sa1 = *(const f32x4*)(gA + 36);
  sb0 = *(const f32x4*)(gA + (size_t)16*EMB + 32);
  sb1 = *(const f32x4*)(gA + (size_t)16*EMB + 36);
  glds16(gB + 32, &Bs[1][w*32][0]);
  glds16(gB + (size_t)16*EMB + 32, &Bs[1][w*32 + 16][0]);
  __syncthreads();

  const int fswz = (g ^ ((l16 >> 1) & 3)) * 8;

#pragma unroll 2
  for (int i = 0; i < 32; ++i) {
    const int cur = i & 1;
    if (i < 30) {
      const int k0 = (i + 2) * 32;
      ra0 = *(const f32x4*)(gA + k0);
      ra1 = *(const f32x4*)(gA + k0 + 4);
      rb0 = *(const f32x4*)(gA + (size_t)16*EMB + k0);
      rb1 = *(const f32x4*)(gA + (size_t)16*EMB + k0 + 4);
    }
    if (i < 31) {
      const int k0 = (i + 1) * 32;
      glds16(gB + k0, &Bs[cur ^ 1][w*32][0]);
      glds16(gB + (size_t)16*EMB + k0, &Bs[cur ^ 1][w*32 + 16][0]);
    }

    h8 af[4], bfr[4];
#pragma unroll
    for (int m = 0; m < 4; ++m) af[m]  = *(const h8*)&As[cur][wr*64 + m*16 + l16][fswz];
#pragma unroll
    for (int n = 0; n < 4; ++n) bfr[n] = *(const h8*)&Bs[cur][wc*64 + n*16 + l16][fswz];
    __builtin_amdgcn_s_setprio(1);
#pragma unroll
    for (int m = 0; m < 4; ++m)
#pragma unroll
      for (int n = 0; n < 4; ++n)
        acc[m][n] = __builtin_amdgcn_mfma_f32_16x16x32_f16(af[m], bfr[n], acc[m][n], 0, 0, 0);
    __builtin_amdgcn_s_setprio(0);

    if (i < 31) {
      f16* d0 = lA0  + (cur ^ 1) * asStride;
      f16* d1 = lA0b + (cur ^ 1) * asStride;
      *(h8*)d0 = pack8(sa0, sa1);
      *(h8*)d1 = pack8(sb0, sb1);
      sa0 = ra0; sa1 = ra1; sb0 = rb0; sb1 = rb1;
    }
    __syncthreads();
  }

#pragma unroll
  for (int m = 0; m < 4; ++m) {
#pragma unroll
    for (int n = 0; n < 4; ++n) {
      const int col = bn + wc*64 + n*16 + l16;
      const float bv = bias[col];
#pragma unroll
      for (int r = 0; r < 4; ++r) {
        const int row = bm + wr*64 + m*16 + g*4 + r;
        float v = acc[m][n][r] + bv;
        if (z == 0) v *= QSCALE;
        const int l = row >> 2, nn = row & 3;
        const int h = col >> 6, hd = col & 63;
        Hbase[(((size_t)z * BH + nn * NHEAD + h) * L_SEQ + l) * HDIM + hd] = (f16)v;
      }
    }
  }
}

// ---------------- out-proj GEMM (f16 A), dbuf, A+B bank-swizzled ----------------
__global__ __launch_bounds__(256)
void gemm_out(const f16* __restrict__ A, const f16* __restrict__ Bt,
              const float* __restrict__ bias, float* __restrict__ Fout)
{
  const int id = blockIdx.x;
  const int x   = id & 7;
  const int bnI = (id >> 3) & 7;
  const int bmG = x + 8 * (id >> 6);   // 0..63
  const int bm  = bmG * 128;
  const int bn  = bnI * 128;

  const int t = threadIdx.x;
  const int w = t >> 6, lane = t & 63;
  const int wr = w >> 1, wc = w & 1;
  const int l16 = lane & 15, g = lane >> 4;

  __shared__ f16 As[2][128][32];
  __shared__ f16 Bs[2][128][32];

  f32x4 acc[4][4] = {};

  const int sr  = lane >> 2;
  const int sc8 = 8 * ((lane & 3) ^ ((lane >> 3) & 3));
  const f16* gA = &A [(size_t)(bm + w*32 + sr) * EMB + sc8];
  const f16* gB = &Bt[(size_t)(bn + w*32 + sr) * EMB + sc8];

  glds16(gA, &As[0][w*32][0]);
  glds16(gA + (size_t)16*EMB, &As[0][w*32 + 16][0]);
  glds16(gB, &Bs[0][w*32][0]);
  glds16(gB + (size_t)16*EMB, &Bs[0][w*32 + 16][0]);
  __syncthreads();

  const int fswz = (g ^ ((l16 >> 1) & 3)) * 8;

#pragma unroll 1
  for (int i = 0; i < 32; ++i) {
    const int cur = i & 1;
    if (i < 31) {
      const int k0 = (i + 1) * 32;
      glds16(gA + k0, &As[cur ^ 1][w*32][0]);
      glds16(gA + (size_t)16*EMB + k0, &As[cur ^ 1][w*32 + 16][0]);
      glds16(gB + k0, &Bs[cur ^ 1][w*32][0]);
      glds16(gB + (size_t)16*EMB + k0, &Bs[cur ^ 1][w*32 + 16][0]);
    }

    h8 af[4], bfr[4];
#pragma unroll
    for (int m = 0; m < 4; ++m) af[m]  = *(const h8*)&As[cur][wr*64 + m*16 + l16][fswz];
#pragma unroll
    for (int n = 0; n < 4; ++n) bfr[n] = *(const h8*)&Bs[cur][wc*64 + n*16 + l16][fswz];
    __builtin_amdgcn_s_setprio(1);
#pragma unroll
    for (int m = 0; m < 4; ++m)
#pragma unroll
      for (int n = 0; n < 4; ++n)
        acc[m][n] = __builtin_amdgcn_mfma_f32_16x16x32_f16(af[m], bfr[n], acc[m][n], 0, 0, 0);
    __builtin_amdgcn_s_setprio(0);
    __syncthreads();
  }

#pragma unroll
  for (int m = 0; m < 4; ++m) {
#pragma unroll
    for (int n = 0; n < 4; ++n) {
      const int col = bn + wc*64 + n*16 + l16;
      const float bv = bias[col];
#pragma unroll
      for (int r = 0; r < 4; ++r) {
        const int row = bm + wr*64 + m*16 + g*4 + r;
        Fout[(size_t)row * EMB + col] = acc[m][n][r] + bv;
      }
    }
  }
}

// ---------------- V transpose: [BH][L][HD] -> [BH][HD][L] ----------------
__global__ __launch_bounds__(256)
void vtrans_kernel(const f16* __restrict__ V, f16* __restrict__ Vt) {
  const int b = blockIdx.y;
  const int t = threadIdx.x;
  const int d = t & 63;
  const int l0 = (blockIdx.x * 4 + (t >> 6)) * 8;
  const f16* Vb = V  + (size_t)b * L_SEQ * HDIM;
  f16* Vtb      = Vt + (size_t)b * L_SEQ * HDIM;
  h8 v;
#pragma unroll
  for (int i = 0; i < 8; ++i) v[i] = Vb[(size_t)(l0 + i) * HDIM + d];
  *(h8*)&Vtb[(size_t)d * L_SEQ + l0] = v;
}

// ---------------- Flash attention v12: 2 q-tiles per wave (verified best) ----------------
__device__ __forceinline__ void expack(const f32x16& acc, float (&ps)[4],
                                       h8& paA, h8& paB) {
#pragma unroll
  for (int half = 0; half < 2; ++half) {
    float p0 = __builtin_amdgcn_exp2f(acc[half*8+0]);
    float p1 = __builtin_amdgcn_exp2f(acc[half*8+1]);
    float p2 = __builtin_amdgcn_exp2f(acc[half*8+2]);
    float p3 = __builtin_amdgcn_exp2f(acc[half*8+3]);
    float p4 = __builtin_amdgcn_exp2f(acc[half*8+4]);
    float p5 = __builtin_amdgcn_exp2f(acc[half*8+5]);
    float p6 = __builtin_amdgcn_exp2f(acc[half*8+6]);
    float p7 = __builtin_amdgcn_exp2f(acc[half*8+7]);
    ps[0] += p0 + p4;
    ps[1] += p1 + p5;
    ps[2] += p2 + p6;
    ps[3] += p3 + p7;
    unsigned A = pkrtz(p0, p1);
    unsigned C = pkrtz(p2, p3);
    unsigned B = pkrtz(p4, p5);
    unsigned D = pkrtz(p6, p7);
    asm("v_permlane32_swap_b32 %0, %1" : "+v"(A), "+v"(B));
    asm("v_permlane32_swap_b32 %0, %1" : "+v"(C), "+v"(D));
    u32x4 wv = { A, C, B, D };
    h8 r = __builtin_bit_cast(h8, wv);
    if (half == 0) paA = r; else paB = r;
  }
}

__device__ __forceinline__ void attn12_step(
    const f16* __restrict__ Kc, const f16* __restrict__ Vc,
    const h8 (&qf0)[4], const h8 (&qf1)[4],
    f32x16 (&o0)[2], f32x16 (&o1)[2],
    float (&ps0)[4], float (&ps1)[4],
    int l31, int hi)
{
  const int swz = (l31 & 7) << 3;

  h8 pa0[4], pa1[4];
#pragma unroll
  for (int kt = 0; kt < 2; ++kt) {
    h8 kf[4];
#pragma unroll
    for (int s = 0; s < 4; ++s)
      kf[s] = *(const h8*)&Kc[(kt*32 + l31)*64 + ((s*16 + hi*8) ^ swz)];

    f32x16 acc0 = {};
    f32x16 acc1 = {};
    __builtin_amdgcn_s_setprio(1);
#pragma unroll
    for (int s = 0; s < 4; ++s) {
      acc0 = MFMA32(kf[s], qf0[s], acc0);
      acc1 = MFMA32(kf[s], qf1[s], acc1);
    }
    __builtin_amdgcn_s_setprio(0);

    expack(acc0, ps0, pa0[kt*2], pa0[kt*2+1]);
    expack(acc1, ps1, pa1[kt*2], pa1[kt*2+1]);
  }

#pragma unroll
  for (int s2 = 0; s2 < 4; ++s2) {
    h8 vf0 = *(const h8*)&Vc[(0*32 + l31)*64 + ((s2*16 + hi*8) ^ swz)];
    h8 vf1 = *(const h8*)&Vc[(1*32 + l31)*64 + ((s2*16 + hi*8) ^ swz)];
    __builtin_amdgcn_s_setprio(1);
    o0[0] = MFMA32(pa0[s2], vf0, o0[0]);
    o0[1] = MFMA32(pa0[s2], vf1, o0[1]);
    o1[0] = MFMA32(pa1[s2], vf0, o1[0]);
    o1[1] = MFMA32(pa1[s2], vf1, o1[1]);
    __builtin_amdgcn_s_setprio(0);
  }
}

__global__ __launch_bounds__(256, 2)
void attn12_kernel(const f16* __restrict__ Qh, const f16* __restrict__ Kh,
                   const f16* __restrict__ Vt, f16* __restrict__ AO)
{
  // 512 blocks: 8 XCD x 8 qblk x 8 head-groups; 8 heads per XCD (L2 locality)
  const int id = blockIdx.x;
  const int b    = (id & 7) | ((id >> 6) << 3);
  const int qblk = (id >> 3) & 7;

  const int t = threadIdx.x;
  const int w = t >> 6, lane = t & 63;
  const int l31 = lane & 31, hi = lane >> 5;

  const f16* Qb = Qh + (size_t)b * L_SEQ * HDIM;
  const f16* Kb = Kh + (size_t)b * L_SEQ * HDIM;
  const f16* Vb = Vt + (size_t)b * (size_t)HDIM * L_SEQ;

  __shared__ f16 Ks[2][64*64];
  __shared__ f16 Vs[2][64*64];

  const int q0 = qblk * 256 + w * 32;   // this wave's q-tiles: q0 and q0+128

  h8 qf0[4], qf1[4];
#pragma unroll
  for (int s = 0; s < 4; ++s) {
    qf0[s] = *(const h8*)&Qb[(size_t)(q0 + l31) * HDIM + s*16 + hi*8];
    qf1[s] = *(const h8*)&Qb[(size_t)(q0 + 128 + l31) * HDIM + s*16 + hi*8];
  }

  const int srow = lane >> 3;
  const int scol = 8 * ((lane & 7) ^ srow);
  const int r0   = w*16 + srow;
  const f16* gK0 = Kb + (size_t)(r0    ) * HDIM + scol;
  const f16* gK1 = Kb + (size_t)(r0 + 8) * HDIM + scol;
  const f16* gV0 = Vb + (size_t)(r0    ) * L_SEQ + scol;
  const f16* gV1 = Vb + (size_t)(r0 + 8) * L_SEQ + scol;
  const int ldsw = w * 1024;

  f32x16 o0[2] = {};
  f32x16 o1[2] = {};
  float ps0[4] = { 0.f, 0.f, 0.f, 0.f };
  float ps1[4] = { 0.f, 0.f, 0.f, 0.f };

  glds16(gK0, &Ks[0][ldsw]);
  glds16(gK1, &Ks[0][ldsw + 512]);
  glds16(gV0, &Vs[0][ldsw]);
  glds16(gV1, &Vs[0][ldsw + 512]);
  __syncthreads();

#pragma unroll 1
  for (int j0 = 0; j0 < L_SEQ; j0 += 128) {
    {
      const int jn = (j0 + 64) & (L_SEQ - 1);
      glds16(gK0 + (size_t)jn * HDIM, &Ks[1][ldsw]);
      glds16(gK1 + (size_t)jn * HDIM, &Ks[1][ldsw + 512]);
      glds16(gV0 + jn, &Vs[1][ldsw]);
      glds16(gV1 + jn, &Vs[1][ldsw + 512]);
      attn12_step(&Ks[0][0], &Vs[0][0], qf0, qf1, o0, o1, ps0, ps1, l31, hi);
      __syncthreads();
    }
    {
      const int jn = (j0 + 128) & (L_SEQ - 1);
      glds16(gK0 + (size_t)jn * HDIM, &Ks[0][ldsw]);
      glds16(gK1 + (size_t)jn * HDIM, &Ks[0][ldsw + 512]);
      glds16(gV0 + jn, &Vs[0][ldsw]);
      glds16(gV1 + jn, &Vs[0][ldsw + 512]);
      attn12_step(&Ks[1][0], &Vs[1][0], qf0, qf1, o0, o1, ps0, ps1, l31, hi);
      __syncthreads();
    }
  }

  // ---- epilogue (two q-tiles) ----
  const int nn = b >> 4, h = b & 15;
  float ssum0 = (ps0[0] + ps0[1]) + (ps0[2] + ps0[3]);
  ssum0 += __shfl_xor(ssum0, 32);
  const float inv0 = 1.0f / ssum0;
  float ssum1 = (ps1[0] + ps1[1]) + (ps1[2] + ps1[3]);
  ssum1 += __shfl_xor(ssum1, 32);
  const float inv1 = 1.0f / ssum1;

#pragma unroll
  for (int r = 0; r < 16; ++r) {
    const int qrow = (r & 3) + 8 * (r >> 2) + 4 * hi;
    {
      const float iv = __shfl(inv0, qrow);
      const int lr = q0 + qrow;
#pragma unroll
      for (int dt = 0; dt < 2; ++dt)
        AO[((size_t)lr * NBATCH + nn) * EMB + h*HDIM + dt*32 + l31] =
            (f16)(o0[dt][r] * iv);
    }
    {
      const float iv = __shfl(inv1, qrow);
      const int lr = q0 + 128 + qrow;
#pragma unroll
      for (int dt = 0; dt < 2; ++dt)
        AO[((size_t)lr * NBATCH + nn) * EMB + h*HDIM + dt*32 + l31] =
            (f16)(o1[dt][r] * iv);
    }
  }
}

// ---------------- launch ----------------
extern "C" void kernel_launch(void* const* d_in, const int* in_sizes, int n_in,
                              void* d_out, int out_size, void* d_ws, size_t ws_size,
                              hipStream_t stream) {
  const float* query = (const float*)d_in[0];
  const float* key   = (const float*)d_in[1];
  const float* value = (const float*)d_in[2];
  const float* in_w  = (const float*)d_in[3];
  const float* in_b  = (const float*)d_in[4];
  const float* out_w = (const float*)d_in[5];
  const float* out_b = (const float*)d_in[6];
  float* out = (float*)d_out;

  char* ws = (char*)d_ws;
  size_t offH  = 0;
  size_t offX  = offH  + (size_t)3 * BH * L_SEQ * HDIM * 2;
  size_t offW  = offX  + (size_t)3 * MROWS * EMB * 2;
  size_t offWo = offW  + (size_t)3 * EMB * EMB * 2;
  size_t offAO = offWo + (size_t)EMB * EMB * 2;
  f16* Hbase = (f16*)(ws + offH);
  f16* Xb    = (f16*)(ws + offX);   // region reused for Vt only
  f16* Wb    = (f16*)(ws + offW);
  f16* Wob   = (f16*)(ws + offWo);
  f16* AOb   = (f16*)(ws + offAO);
  f16* Vtb   = Xb;

  hipLaunchKernelGGL(convert_w_kernel, dim3(1024), dim3(256), 0, stream,
                     in_w, out_w, Wb, Wob);

  hipLaunchKernelGGL(gemm_qkv, dim3(1536), dim3(256), 0, stream,
                     query, key, value, Wb, in_b, Hbase);

  f16* Vh = Hbase + (size_t)2 * BH * L_SEQ * HDIM;
  hipLaunchKernelGGL(vtrans_kernel, dim3(L_SEQ/32, BH), dim3(256), 0, stream, Vh, Vtb);

  hipLaunchKernelGGL(attn12_kernel, dim3(512), dim3(256), 0, stream,
                     Hbase,
                     Hbase + (size_t)BH * L_SEQ * HDIM,
                     Vtb, AOb);

  hipLaunchKernelGGL(gemm_out, dim3(512), dim3(256), 0, stream,
                     AOb, Wob, out_b, out);
}